// Round 6
// baseline (267.143 us; speedup 1.0000x reference)
//
#include <hip/hip_runtime.h>
#include <hip/hip_bf16.h>

// RelationalMemoryCoreCell on MI355X (gfx950).
// B=256, S=16, H=8, HS=128, D=1024, M=1024, R=B*S=4096.
// Inputs fp32, outputs fp32. All GEMMs: bf16 MFMA 16x16x32, m97 128x128 tile.
//
// Pipeline:
//   k_cvt(h)->hbf, k_cvt(x)->xbf, k_transpose_w -> wt (8 planes [N][K] bf16)
//   k_gemm_big: h@[Wuf|Wui|Wuo] -> pre (bf16, 3 planes)  AND
//               x@[Wemb|Wwf|Wwi|Wwo] -> proj (fp32, dense gets +b_emb)
//   k_attn: dense + m_state -> mpb (bf16, overwrites hbf slot)
//   k_out:  mp@W_g (fused full gate epilogue) -> out_mem, out_hid
//
// Workspace (53 MB):
//   [0,  4MB): proj fp32: dense | xf | xi | xo   (4 x 262144 floats)
//   [4, 12MB): hbf bf16 [4096][1024]  -> later overwritten by mpb
//   [12,28MB): wt bf16 8 x [1024][1024]: W_g,W_uf,W_ui,W_uo,W_emb,W_wf,W_wi,W_wo
//   [28,28.5MB): xbf bf16 [256][1024]
//   [29,53MB): pre bf16 3 x [4096][1024]  (h@Wuf, h@Wui, h@Wuo)

typedef __hip_bfloat16 bf16;
typedef __bf16 bf16x8 __attribute__((ext_vector_type(8)));
typedef float  f32x4  __attribute__((ext_vector_type(4)));

__device__ __forceinline__ float b2f(bf16 x) { return __bfloat162float(x); }
__device__ __forceinline__ bf16  f2b(float x) { return __float2bfloat16(x); }
__device__ __forceinline__ float sig(float x) { return 1.0f / (1.0f + __expf(-x)); }

__device__ __forceinline__ void gl_lds16(const void* g, void* l) {
    __builtin_amdgcn_global_load_lds(
        (const __attribute__((address_space(1))) void*)g,
        (__attribute__((address_space(3))) void*)l,
        16, 0, 0);
}

// ---------------------------------------------------------------------------
// prep: fp32 -> bf16 cast
// ---------------------------------------------------------------------------
__global__ __launch_bounds__(256) void k_cvt(
    const float* __restrict__ src, bf16* __restrict__ dst)
{
    int idx = (blockIdx.x * 256 + threadIdx.x) * 4;
    float4 v = *(const float4*)(src + idx);
    dst[idx + 0] = f2b(v.x);
    dst[idx + 1] = f2b(v.y);
    dst[idx + 2] = f2b(v.z);
    dst[idx + 3] = f2b(v.w);
}

// ---------------------------------------------------------------------------
// prep: transpose 8 weights [K=1024][N=1024] fp32 -> [N][K] bf16
// ---------------------------------------------------------------------------
__global__ __launch_bounds__(256) void k_transpose_w(
    const float* __restrict__ W0, const float* __restrict__ W1,
    const float* __restrict__ W2, const float* __restrict__ W3,
    const float* __restrict__ W4, const float* __restrict__ W5,
    const float* __restrict__ W6, const float* __restrict__ W7,
    bf16* __restrict__ wt)
{
    const float* Ws[8] = {W0, W1, W2, W3, W4, W5, W6, W7};
    const float* W = Ws[blockIdx.z];
    bf16* Wt = wt + (size_t)blockIdx.z * (1024 * 1024);

    __shared__ float t[32][33];
    const int tx = threadIdx.x, ty = threadIdx.y;
    const int nb = blockIdx.x * 32, kb = blockIdx.y * 32;

    #pragma unroll
    for (int r = 0; r < 4; ++r)
        t[r * 8 + ty][tx] = W[(size_t)(kb + r * 8 + ty) * 1024 + nb + tx];
    __syncthreads();
    #pragma unroll
    for (int r = 0; r < 4; ++r)
        Wt[(size_t)(nb + r * 8 + ty) * 1024 + kb + tx] = f2b(t[tx][r * 8 + ty]);
}

// ---------------------------------------------------------------------------
// GEMM-1: 832 blocks, 128x128 tile, BK=64.
//   bid <  768: recurrent gates: A=hbf, m0=(bid/24)*128, n=(bid%24)*128 in
//               [0,3072) -> plane 1+(n>>10) of wt, writes pre[(n>>10)] bf16.
//   bid >= 768: input proj: A=xbf (256 rows), n in [0,4096) -> plane 4+(n>>10),
//               writes proj fp32 (plane 0 dense gets +b_emb).
// LDS 32KB: sA[128][64] @0, sB[128][64] @16K.
// ---------------------------------------------------------------------------
__global__ __launch_bounds__(256) void k_gemm_big(
    const bf16* __restrict__ hbf,
    const bf16* __restrict__ xbf,
    const bf16* __restrict__ wt,
    const float* __restrict__ b_emb,
    bf16* __restrict__ pre,
    float* __restrict__ proj)
{
    __shared__ __align__(16) char smem[32768];

    const int bid = blockIdx.x;
    const int wv = threadIdx.x >> 6;
    const int lane = threadIdx.x & 63;
    const int r8 = lane >> 3, c8 = lane & 7;
    const int mrow = lane & 15, q = lane >> 4;

    const bf16* A;
    int m0, plane, bn0;
    if (bid < 768) {
        int bx = bid % 24, by = bid / 24;
        A = hbf; m0 = by * 128;
        int n0g = bx * 128;
        plane = 1 + (n0g >> 10); bn0 = n0g & 1023;
    } else {
        int e = bid - 768;
        int bx = e & 31, by = e >> 5;
        A = xbf; m0 = by * 128;
        int n0x = bx * 128;
        plane = 4 + (n0x >> 10); bn0 = n0x & 1023;
    }
    const bf16* Bp = wt + (size_t)plane * (1024 * 1024);

    const f32x4 zero4 = {0.0f, 0.0f, 0.0f, 0.0f};
    f32x4 acc[4][4];
    #pragma unroll
    for (int i = 0; i < 4; ++i)
        #pragma unroll
        for (int j = 0; j < 4; ++j) acc[i][j] = zero4;

    const int rb = (wv & 1) * 64, cb = (wv >> 1) * 64;

    for (int k0 = 0; k0 < 1024; k0 += 64) {
        #pragma unroll
        for (int t = 0; t < 4; ++t) {
            int rr = wv * 32 + t * 8;
            gl_lds16(A  + (size_t)(m0  + rr + r8) * 1024 + k0 + c8 * 8, smem + rr * 128);
            gl_lds16(Bp + (size_t)(bn0 + rr + r8) * 1024 + k0 + c8 * 8, smem + 16384 + rr * 128);
        }
        __syncthreads();

        #pragma unroll
        for (int kk = 0; kk < 2; ++kk) {
            const int kb = kk * 64 + q * 16;
            bf16x8 a[4], b[4];
            #pragma unroll
            for (int i = 0; i < 4; ++i)
                a[i] = *(const bf16x8*)(smem + (rb + i * 16 + mrow) * 128 + kb);
            #pragma unroll
            for (int j = 0; j < 4; ++j)
                b[j] = *(const bf16x8*)(smem + 16384 + (cb + j * 16 + mrow) * 128 + kb);
            #pragma unroll
            for (int i = 0; i < 4; ++i)
                #pragma unroll
                for (int j = 0; j < 4; ++j)
                    acc[i][j] = __builtin_amdgcn_mfma_f32_16x16x32_bf16(a[i], b[j], acc[i][j], 0, 0, 0);
        }
        __syncthreads();
    }

    if (bid < 768) {
        bf16* P = pre + (size_t)(plane - 1) * (4096 * 1024);
        #pragma unroll
        for (int j = 0; j < 4; ++j) {
            const int colp = bn0 + cb + j * 16 + mrow;
            #pragma unroll
            for (int i = 0; i < 4; ++i)
                #pragma unroll
                for (int r = 0; r < 4; ++r) {
                    const int row = m0 + rb + i * 16 + q * 4 + r;
                    P[(size_t)row * 1024 + colp] = f2b(acc[i][j][r]);
                }
        }
    } else {
        const int which = plane - 4;
        float* P = proj + which * 262144;
        #pragma unroll
        for (int j = 0; j < 4; ++j) {
            const int colp = bn0 + cb + j * 16 + mrow;
            const float bias = (which == 0) ? b_emb[colp] : 0.0f;
            #pragma unroll
            for (int i = 0; i < 4; ++i)
                #pragma unroll
                for (int r = 0; r < 4; ++r) {
                    const int row = m0 + rb + i * 16 + q * 4 + r;
                    P[(size_t)row * 1024 + colp] = acc[i][j][r] + bias;
                }
        }
    }
}

// ---------------------------------------------------------------------------
// attention per (b,h) -> mpb bf16 (vectorized, padded kv rows)
// ---------------------------------------------------------------------------
__global__ __launch_bounds__(256) void k_attn(
    const float* __restrict__ m_state,
    const float* __restrict__ dense,
    bf16* __restrict__ mp)
{
    const int b = blockIdx.x >> 3;
    const int h = blockIdx.x & 7;
    const int tid = threadIdx.x;

    __shared__ float kv[17][132];
    __shared__ float sc[16][18];

    for (int idx = tid; idx < 17 * 32; idx += 256) {
        int r = idx >> 5, d4 = idx & 31;
        const float* src = (r < 16)
            ? &m_state[(size_t)(b * 16 + r) * 1024 + h * 128 + d4 * 4]
            : &dense[(size_t)b * 1024 + h * 128 + d4 * 4];
        float4 v = *(const float4*)src;
        *(float4*)&kv[r][d4 * 4] = v;
    }
    __syncthreads();

    for (int p = tid; p < 16 * 17; p += 256) {
        int qi = p / 17, ki = p % 17;
        float dx = 0.f, dy = 0.f, dz = 0.f, dw = 0.f;
        #pragma unroll 8
        for (int d4 = 0; d4 < 32; ++d4) {
            float4 a = *(const float4*)&kv[qi][d4 * 4];
            float4 c = *(const float4*)&kv[ki][d4 * 4];
            dx += a.x * c.x; dy += a.y * c.y; dz += a.z * c.z; dw += a.w * c.w;
        }
        sc[qi][ki] = (dx + dy + dz + dw) * 0.0883883476483184f;
    }
    __syncthreads();

    if (tid < 16) {
        float mx = -1e30f;
        for (int k = 0; k < 17; ++k) mx = fmaxf(mx, sc[tid][k]);
        float s = 0.0f;
        for (int k = 0; k < 17; ++k) { float e = __expf(sc[tid][k] - mx); sc[tid][k] = e; s += e; }
        float inv = 1.0f / s;
        for (int k = 0; k < 17; ++k) sc[tid][k] *= inv;
    }
    __syncthreads();

    for (int p = tid; p < 16 * 32; p += 256) {
        int qi = p >> 5, d4 = p & 31;
        float sx = 0.f, sy = 0.f, sz = 0.f, sw = 0.f;
        #pragma unroll
        for (int k = 0; k < 17; ++k) {
            float w = sc[qi][k];
            float4 v = *(const float4*)&kv[k][d4 * 4];
            sx += w * v.x; sy += w * v.y; sz += w * v.z; sw += w * v.w;
        }
        float4 base = *(const float4*)&kv[qi][d4 * 4];
        size_t off = (size_t)(b * 16 + qi) * 1024 + h * 128 + d4 * 4;
        mp[off + 0] = f2b(base.x + sx);
        mp[off + 1] = f2b(base.y + sy);
        mp[off + 2] = f2b(base.z + sz);
        mp[off + 3] = f2b(base.w + sw);
    }
}

// ---------------------------------------------------------------------------
// GEMM-2 + epilogue: mp@W_g, M=4096, N=1024, 128x128 tile, 256 blocks.
// pre_g stays in registers; full gate math fused; writes out_mem/out_hid fp32.
// ---------------------------------------------------------------------------
__global__ __launch_bounds__(256) void k_out(
    const bf16* __restrict__ mpb,
    const bf16* __restrict__ wtg,    // plane 0 of wt (W_g, [N][K])
    const bf16* __restrict__ pre,    // 3 planes [4096][1024]
    const float* __restrict__ m_state,
    const float* __restrict__ proj,  // dense|xf|xi|xo
    const float* __restrict__ b_g, const float* __restrict__ b_uf,
    const float* __restrict__ b_ui, const float* __restrict__ b_uo,
    float* __restrict__ out_mem, float* __restrict__ out_hid)
{
    __shared__ __align__(16) char smem[32768];

    const int n0 = (blockIdx.x & 7) * 128;
    const int m0 = (blockIdx.x >> 3) * 128;
    const int wv = threadIdx.x >> 6;
    const int lane = threadIdx.x & 63;
    const int r8 = lane >> 3, c8 = lane & 7;
    const int mrow = lane & 15, q = lane >> 4;

    const f32x4 zero4 = {0.0f, 0.0f, 0.0f, 0.0f};
    f32x4 acc[4][4];
    #pragma unroll
    for (int i = 0; i < 4; ++i)
        #pragma unroll
        for (int j = 0; j < 4; ++j) acc[i][j] = zero4;

    const int rb = (wv & 1) * 64, cb = (wv >> 1) * 64;

    for (int k0 = 0; k0 < 1024; k0 += 64) {
        #pragma unroll
        for (int t = 0; t < 4; ++t) {
            int rr = wv * 32 + t * 8;
            gl_lds16(mpb + (size_t)(m0 + rr + r8) * 1024 + k0 + c8 * 8, smem + rr * 128);
            gl_lds16(wtg + (size_t)(n0 + rr + r8) * 1024 + k0 + c8 * 8, smem + 16384 + rr * 128);
        }
        __syncthreads();

        #pragma unroll
        for (int kk = 0; kk < 2; ++kk) {
            const int kb = kk * 64 + q * 16;
            bf16x8 a[4], b[4];
            #pragma unroll
            for (int i = 0; i < 4; ++i)
                a[i] = *(const bf16x8*)(smem + (rb + i * 16 + mrow) * 128 + kb);
            #pragma unroll
            for (int j = 0; j < 4; ++j)
                b[j] = *(const bf16x8*)(smem + 16384 + (cb + j * 16 + mrow) * 128 + kb);
            #pragma unroll
            for (int i = 0; i < 4; ++i)
                #pragma unroll
                for (int j = 0; j < 4; ++j)
                    acc[i][j] = __builtin_amdgcn_mfma_f32_16x16x32_bf16(a[i], b[j], acc[i][j], 0, 0, 0);
        }
        __syncthreads();
    }

    const float* xf = proj + 262144;
    const float* xi = proj + 524288;
    const float* xo = proj + 786432;

    #pragma unroll
    for (int j = 0; j < 4; ++j) {
        const int col = n0 + cb + j * 16 + mrow;
        const float bgv  = b_g[col];
        const float bufv = b_uf[col];
        const float buiv = b_ui[col];
        const float buov = b_uo[col];
        #pragma unroll
        for (int i = 0; i < 4; ++i) {
            const int bidx = ((m0 + rb) >> 4) + i;
            const float xfv = xf[bidx * 1024 + col];
            const float xiv = xi[bidx * 1024 + col];
            const float xov = xo[bidx * 1024 + col];
            #pragma unroll
            for (int r = 0; r < 4; ++r) {
                const int row = m0 + rb + i * 16 + q * 4 + r;
                const size_t off = (size_t)row * 1024 + col;
                const float m   = m_state[off];
                const float mpv = b2f(mpb[off]);
                const float mp2 = acc[i][j][r] + bgv + mpv;
                const float fg  = sig(b2f(pre[off])           + bufv + xfv);
                const float ig  = sig(b2f(pre[4194304 + off]) + buiv + xiv);
                const float og  = sig(b2f(pre[8388608 + off]) + buov + xov);
                out_mem[off] = sig(m * fg + 1.0f) + mp2 * sig(ig);
                out_hid[off] = tanhf(m) * sig(og);
            }
        }
    }
}

extern "C" void kernel_launch(void* const* d_in, const int* in_sizes, int n_in,
                              void* d_out, int out_size, void* d_ws, size_t ws_size,
                              hipStream_t stream)
{
    const float* inputs  = (const float*)d_in[0];
    const float* h_state = (const float*)d_in[1];
    const float* m_state = (const float*)d_in[2];
    const float* W_emb   = (const float*)d_in[3];
    const float* b_emb   = (const float*)d_in[4];
    const float* W_g     = (const float*)d_in[5];
    const float* b_g     = (const float*)d_in[6];
    const float* W_wf    = (const float*)d_in[7];
    const float* W_wi    = (const float*)d_in[8];
    const float* W_wo    = (const float*)d_in[9];
    const float* W_uf    = (const float*)d_in[10];
    const float* b_uf    = (const float*)d_in[11];
    const float* W_ui    = (const float*)d_in[12];
    const float* b_ui    = (const float*)d_in[13];
    const float* W_uo    = (const float*)d_in[14];
    const float* b_uo    = (const float*)d_in[15];

    char* wsb = (char*)d_ws;
    float* proj = (float*)wsb;                           // 4 MB
    bf16*  hmp  = (bf16*)(wsb + 4u  * 1048576u);         // 8 MB: hbf, then mpb
    bf16*  wt   = (bf16*)(wsb + 12u * 1048576u);         // 16 MB (8 planes)
    bf16*  xbf  = (bf16*)(wsb + 28u * 1048576u);         // 0.5 MB
    bf16*  pre  = (bf16*)(wsb + 29u * 1048576u);         // 24 MB (3 planes)

    float* out_mem = (float*)d_out;
    float* out_hid = out_mem + (size_t)4096 * 1024;

    // prep
    k_cvt<<<dim3(4096), dim3(256), 0, stream>>>(h_state, hmp);
    k_cvt<<<dim3(256),  dim3(256), 0, stream>>>(inputs, xbf);
    k_transpose_w<<<dim3(32, 32, 8), dim3(32, 8), 0, stream>>>(
        W_g, W_uf, W_ui, W_uo, W_emb, W_wf, W_wi, W_wo, wt);

    // GEMM-1: gate pre-acts (h@Wu*) + input projections (x@W*)
    k_gemm_big<<<dim3(832), dim3(256), 0, stream>>>(
        hmp, xbf, wt, b_emb, pre, proj);

    // attention: dense + m_state -> mp (bf16, overwrites hbf slot)
    k_attn<<<dim3(256 * 8), dim3(256), 0, stream>>>(m_state, proj, hmp);

    // GEMM-2 + fused epilogue: mp@W_g, gates, outputs
    k_out<<<dim3(256), dim3(256), 0, stream>>>(
        hmp, wt, pre, m_state, proj,
        b_g, b_uf, b_ui, b_uo, out_mem, out_hid);
}

// Round 7
// 238.279 us; speedup vs baseline: 1.1211x; 1.1211x over previous
//
#include <hip/hip_runtime.h>
#include <hip/hip_bf16.h>

// RelationalMemoryCoreCell on MI355X (gfx950).
// B=256, S=16, H=8, HS=128, D=1024, M=1024, R=B*S=4096.
// Inputs fp32, outputs fp32. GEMMs: bf16 MFMA 16x16x32 (m97-style tiles).
//
// Pipeline (5 launches):
//   k_prep   : cast h->hbf, x->xbf; transpose 8 weights -> wt [N][K] bf16
//   k_gemm1  : h@[Wuf|Wui|Wuo] -> pre (bf16 x3)  AND  x@[Wemb|Wwf|Wwi|Wwo] -> proj fp32
//   k_attn   : m_state + dense -> mpb (bf16, overwrites hbf)
//   k_gemm2  : mp@W_g -> preg bf16 (pure GEMM, 512 blocks)
//   k_epi    : elementwise gates -> out_mem/out_hid (4096 blocks, coalesced)
//
// Workspace (53 MB):
//   [0,  4MB): proj fp32: dense | xf | xi | xo
//   [4, 12MB): hmp bf16 [4096][1024]   (hbf, later mpb)
//   [12,28MB): wt bf16 8 x [1024][1024]: Wg,Wuf,Wui,Wuo,Wemb,Wwf,Wwi,Wwo
//              -> planes 4..7 (@20MB) are DEAD after gemm1; preg reuses @20MB
//   [28,28.5MB): xbf bf16 [256][1024]
//   [29,53MB): pre bf16 3 x [4096][1024]

typedef __hip_bfloat16 bf16;
typedef __bf16 bf16x8 __attribute__((ext_vector_type(8)));
typedef float  f32x4  __attribute__((ext_vector_type(4)));

__device__ __forceinline__ float b2f(bf16 x) { return __bfloat162float(x); }
__device__ __forceinline__ bf16  f2b(float x) { return __float2bfloat16(x); }
__device__ __forceinline__ float sig(float x) { return 1.0f / (1.0f + __expf(-x)); }

__device__ __forceinline__ void gl_lds16(const void* g, void* l) {
    __builtin_amdgcn_global_load_lds(
        (const __attribute__((address_space(1))) void*)g,
        (__attribute__((address_space(3))) void*)l,
        16, 0, 0);
}

__device__ __forceinline__ float4 ld_bf4(const bf16* p) {
    ushort4 u = *(const ushort4*)p;
    float4 r;
    r.x = b2f(*(const bf16*)&u.x);
    r.y = b2f(*(const bf16*)&u.y);
    r.z = b2f(*(const bf16*)&u.z);
    r.w = b2f(*(const bf16*)&u.w);
    return r;
}

// ---------------------------------------------------------------------------
// k_prep: blocks [0,8192): transpose 8 weights [K][N] fp32 -> [N][K] bf16
//         blocks [8192,10240): cast h_state (4M elems, 8/thread)
//         blocks [10240,10368): cast inputs (256K elems, 8/thread)
// ---------------------------------------------------------------------------
__global__ __launch_bounds__(256) void k_prep(
    const float* __restrict__ W0, const float* __restrict__ W1,
    const float* __restrict__ W2, const float* __restrict__ W3,
    const float* __restrict__ W4, const float* __restrict__ W5,
    const float* __restrict__ W6, const float* __restrict__ W7,
    const float* __restrict__ h_state, const float* __restrict__ inputs,
    bf16* __restrict__ wt, bf16* __restrict__ hbf, bf16* __restrict__ xbf)
{
    const int blk = blockIdx.x;
    const int tid = threadIdx.x;

    if (blk < 8192) {
        const float* Ws[8] = {W0, W1, W2, W3, W4, W5, W6, W7};
        const int plane = blk >> 10;
        const int t = blk & 1023;
        const int nb = (t & 31) * 32, kb = (t >> 5) * 32;
        const float* W = Ws[plane];
        bf16* Wt = wt + (size_t)plane * (1024 * 1024);

        __shared__ float tl[32][33];
        const int tx = tid & 31, ty = tid >> 5;   // 32 x 8

        #pragma unroll
        for (int r = 0; r < 4; ++r)
            tl[r * 8 + ty][tx] = W[(size_t)(kb + r * 8 + ty) * 1024 + nb + tx];
        __syncthreads();
        #pragma unroll
        for (int r = 0; r < 4; ++r)
            Wt[(size_t)(nb + r * 8 + ty) * 1024 + kb + tx] = f2b(tl[tx][r * 8 + ty]);
    } else if (blk < 10240) {
        const int e = blk - 8192;
        int idx = (e * 256 + tid) * 8;
        #pragma unroll
        for (int half = 0; half < 2; ++half) {
            float4 v = *(const float4*)(h_state + idx + half * 4);
            hbf[idx + half * 4 + 0] = f2b(v.x);
            hbf[idx + half * 4 + 1] = f2b(v.y);
            hbf[idx + half * 4 + 2] = f2b(v.z);
            hbf[idx + half * 4 + 3] = f2b(v.w);
        }
    } else {
        const int e = blk - 10240;
        int idx = (e * 256 + tid) * 8;
        #pragma unroll
        for (int half = 0; half < 2; ++half) {
            float4 v = *(const float4*)(inputs + idx + half * 4);
            xbf[idx + half * 4 + 0] = f2b(v.x);
            xbf[idx + half * 4 + 1] = f2b(v.y);
            xbf[idx + half * 4 + 2] = f2b(v.z);
            xbf[idx + half * 4 + 3] = f2b(v.w);
        }
    }
}

// ---------------------------------------------------------------------------
// GEMM-1: 832 blocks, 128x128 tile, BK=64 (validated round 6).
//   bid <  768: gates: A=hbf, writes pre planes bf16.
//   bid >= 768: input proj: A=xbf, writes proj fp32 (dense +b_emb).
// ---------------------------------------------------------------------------
__global__ __launch_bounds__(256) void k_gemm1(
    const bf16* __restrict__ hbf,
    const bf16* __restrict__ xbf,
    const bf16* __restrict__ wt,
    const float* __restrict__ b_emb,
    bf16* __restrict__ pre,
    float* __restrict__ proj)
{
    __shared__ __align__(16) char smem[32768];

    const int bid = blockIdx.x;
    const int wv = threadIdx.x >> 6;
    const int lane = threadIdx.x & 63;
    const int r8 = lane >> 3, c8 = lane & 7;
    const int mrow = lane & 15, q = lane >> 4;

    const bf16* A;
    int m0, plane, bn0;
    if (bid < 768) {
        int bx = bid % 24, by = bid / 24;
        A = hbf; m0 = by * 128;
        int n0g = bx * 128;
        plane = 1 + (n0g >> 10); bn0 = n0g & 1023;
    } else {
        int e = bid - 768;
        int bx = e & 31, by = e >> 5;
        A = xbf; m0 = by * 128;
        int n0x = bx * 128;
        plane = 4 + (n0x >> 10); bn0 = n0x & 1023;
    }
    const bf16* Bp = wt + (size_t)plane * (1024 * 1024);

    const f32x4 zero4 = {0.0f, 0.0f, 0.0f, 0.0f};
    f32x4 acc[4][4];
    #pragma unroll
    for (int i = 0; i < 4; ++i)
        #pragma unroll
        for (int j = 0; j < 4; ++j) acc[i][j] = zero4;

    const int rb = (wv & 1) * 64, cb = (wv >> 1) * 64;

    for (int k0 = 0; k0 < 1024; k0 += 64) {
        #pragma unroll
        for (int t = 0; t < 4; ++t) {
            int rr = wv * 32 + t * 8;
            gl_lds16(A  + (size_t)(m0  + rr + r8) * 1024 + k0 + c8 * 8, smem + rr * 128);
            gl_lds16(Bp + (size_t)(bn0 + rr + r8) * 1024 + k0 + c8 * 8, smem + 16384 + rr * 128);
        }
        __syncthreads();

        #pragma unroll
        for (int kk = 0; kk < 2; ++kk) {
            const int kb = kk * 64 + q * 16;
            bf16x8 a[4], b[4];
            #pragma unroll
            for (int i = 0; i < 4; ++i)
                a[i] = *(const bf16x8*)(smem + (rb + i * 16 + mrow) * 128 + kb);
            #pragma unroll
            for (int j = 0; j < 4; ++j)
                b[j] = *(const bf16x8*)(smem + 16384 + (cb + j * 16 + mrow) * 128 + kb);
            #pragma unroll
            for (int i = 0; i < 4; ++i)
                #pragma unroll
                for (int j = 0; j < 4; ++j)
                    acc[i][j] = __builtin_amdgcn_mfma_f32_16x16x32_bf16(a[i], b[j], acc[i][j], 0, 0, 0);
        }
        __syncthreads();
    }

    if (bid < 768) {
        bf16* P = pre + (size_t)(plane - 1) * (4096 * 1024);
        #pragma unroll
        for (int j = 0; j < 4; ++j) {
            const int colp = bn0 + cb + j * 16 + mrow;
            #pragma unroll
            for (int i = 0; i < 4; ++i)
                #pragma unroll
                for (int r = 0; r < 4; ++r) {
                    const int row = m0 + rb + i * 16 + q * 4 + r;
                    P[(size_t)row * 1024 + colp] = f2b(acc[i][j][r]);
                }
        }
    } else {
        const int which = plane - 4;
        float* P = proj + which * 262144;
        #pragma unroll
        for (int j = 0; j < 4; ++j) {
            const int colp = bn0 + cb + j * 16 + mrow;
            const float bias = (which == 0) ? b_emb[colp] : 0.0f;
            #pragma unroll
            for (int i = 0; i < 4; ++i)
                #pragma unroll
                for (int r = 0; r < 4; ++r) {
                    const int row = m0 + rb + i * 16 + q * 4 + r;
                    P[(size_t)row * 1024 + colp] = acc[i][j][r] + bias;
                }
        }
    }
}

// ---------------------------------------------------------------------------
// attention per (b,h) -> mpb bf16
// ---------------------------------------------------------------------------
__global__ __launch_bounds__(256) void k_attn(
    const float* __restrict__ m_state,
    const float* __restrict__ dense,
    bf16* __restrict__ mp)
{
    const int b = blockIdx.x >> 3;
    const int h = blockIdx.x & 7;
    const int tid = threadIdx.x;

    __shared__ float kv[17][132];
    __shared__ float sc[16][18];

    for (int idx = tid; idx < 17 * 32; idx += 256) {
        int r = idx >> 5, d4 = idx & 31;
        const float* src = (r < 16)
            ? &m_state[(size_t)(b * 16 + r) * 1024 + h * 128 + d4 * 4]
            : &dense[(size_t)b * 1024 + h * 128 + d4 * 4];
        float4 v = *(const float4*)src;
        *(float4*)&kv[r][d4 * 4] = v;
    }
    __syncthreads();

    for (int p = tid; p < 16 * 17; p += 256) {
        int qi = p / 17, ki = p % 17;
        float dx = 0.f, dy = 0.f, dz = 0.f, dw = 0.f;
        #pragma unroll 8
        for (int d4 = 0; d4 < 32; ++d4) {
            float4 a = *(const float4*)&kv[qi][d4 * 4];
            float4 c = *(const float4*)&kv[ki][d4 * 4];
            dx += a.x * c.x; dy += a.y * c.y; dz += a.z * c.z; dw += a.w * c.w;
        }
        sc[qi][ki] = (dx + dy + dz + dw) * 0.0883883476483184f;
    }
    __syncthreads();

    if (tid < 16) {
        float mx = -1e30f;
        for (int k = 0; k < 17; ++k) mx = fmaxf(mx, sc[tid][k]);
        float s = 0.0f;
        for (int k = 0; k < 17; ++k) { float e = __expf(sc[tid][k] - mx); sc[tid][k] = e; s += e; }
        float inv = 1.0f / s;
        for (int k = 0; k < 17; ++k) sc[tid][k] *= inv;
    }
    __syncthreads();

    for (int p = tid; p < 16 * 32; p += 256) {
        int qi = p >> 5, d4 = p & 31;
        float sx = 0.f, sy = 0.f, sz = 0.f, sw = 0.f;
        #pragma unroll
        for (int k = 0; k < 17; ++k) {
            float w = sc[qi][k];
            float4 v = *(const float4*)&kv[k][d4 * 4];
            sx += w * v.x; sy += w * v.y; sz += w * v.z; sw += w * v.w;
        }
        float4 base = *(const float4*)&kv[qi][d4 * 4];
        size_t off = (size_t)(b * 16 + qi) * 1024 + h * 128 + d4 * 4;
        mp[off + 0] = f2b(base.x + sx);
        mp[off + 1] = f2b(base.y + sy);
        mp[off + 2] = f2b(base.z + sz);
        mp[off + 3] = f2b(base.w + sw);
    }
}

// ---------------------------------------------------------------------------
// GEMM-2: mp@W_g -> preg bf16. M=4096, N=1024. 64x128 tile, BK=64,
// 512 blocks (2/CU). Wave grid 2x2: wave owns 32 rows x 64 cols (acc 2x4).
// LDS 24KB: sA[64][64] @0, sB[128][64] @8K.
// ---------------------------------------------------------------------------
__global__ __launch_bounds__(256) void k_gemm2(
    const bf16* __restrict__ mpb,
    const bf16* __restrict__ wtg,    // wt plane 0 (W_g, [N][K])
    bf16* __restrict__ preg)
{
    __shared__ __align__(16) char smem[24576];

    const int m0 = (blockIdx.x >> 3) * 64;
    const int n0 = (blockIdx.x & 7) * 128;
    const int wv = threadIdx.x >> 6;
    const int lane = threadIdx.x & 63;
    const int r8 = lane >> 3, c8 = lane & 7;
    const int mrow = lane & 15, q = lane >> 4;

    const f32x4 zero4 = {0.0f, 0.0f, 0.0f, 0.0f};
    f32x4 acc[2][4];
    #pragma unroll
    for (int i = 0; i < 2; ++i)
        #pragma unroll
        for (int j = 0; j < 4; ++j) acc[i][j] = zero4;

    const int rb = (wv & 1) * 32, cb = (wv >> 1) * 64;

    for (int k0 = 0; k0 < 1024; k0 += 64) {
        #pragma unroll
        for (int t = 0; t < 2; ++t) {
            int rr = wv * 16 + t * 8;
            gl_lds16(mpb + (size_t)(m0 + rr + r8) * 1024 + k0 + c8 * 8, smem + rr * 128);
        }
        #pragma unroll
        for (int t = 0; t < 4; ++t) {
            int rr = wv * 32 + t * 8;
            gl_lds16(wtg + (size_t)(n0 + rr + r8) * 1024 + k0 + c8 * 8, smem + 8192 + rr * 128);
        }
        __syncthreads();

        #pragma unroll
        for (int kk = 0; kk < 2; ++kk) {
            const int kb = kk * 64 + q * 16;
            bf16x8 a[2], b[4];
            #pragma unroll
            for (int i = 0; i < 2; ++i)
                a[i] = *(const bf16x8*)(smem + (rb + i * 16 + mrow) * 128 + kb);
            #pragma unroll
            for (int j = 0; j < 4; ++j)
                b[j] = *(const bf16x8*)(smem + 8192 + (cb + j * 16 + mrow) * 128 + kb);
            #pragma unroll
            for (int i = 0; i < 2; ++i)
                #pragma unroll
                for (int j = 0; j < 4; ++j)
                    acc[i][j] = __builtin_amdgcn_mfma_f32_16x16x32_bf16(a[i], b[j], acc[i][j], 0, 0, 0);
        }
        __syncthreads();
    }

    #pragma unroll
    for (int j = 0; j < 4; ++j) {
        const int col = n0 + cb + j * 16 + mrow;
        #pragma unroll
        for (int i = 0; i < 2; ++i)
            #pragma unroll
            for (int r = 0; r < 4; ++r) {
                const int row = m0 + rb + i * 16 + q * 4 + r;
                preg[(size_t)row * 1024 + col] = f2b(acc[i][j][r]);
            }
    }
}

// ---------------------------------------------------------------------------
// Epilogue: elementwise over 4M outputs, 4 elems/thread, fully coalesced.
//   mp2 = preg + b_g + mp
//   f=sig(pre_f+b_uf+xf); i=sig(pre_i+b_ui+xi); o=sig(pre_o+b_uo+xo)
//   out_mem = sig(m*f+1) + mp2*sig(i);  out_hid = tanh(m)*sig(o)
// ---------------------------------------------------------------------------
__global__ __launch_bounds__(256) void k_epi(
    const float* __restrict__ m_state,
    const bf16* __restrict__ mpb,
    const bf16* __restrict__ preg,
    const bf16* __restrict__ pre,     // 3 planes
    const float* __restrict__ proj,   // dense|xf|xi|xo
    const float* __restrict__ b_g, const float* __restrict__ b_uf,
    const float* __restrict__ b_ui, const float* __restrict__ b_uo,
    float* __restrict__ out_mem, float* __restrict__ out_hid)
{
    const int idx = (blockIdx.x * 256 + threadIdx.x) * 4;
    const int row = idx >> 10;
    const int col = idx & 1023;
    const int b = row >> 4;

    float4 m4  = *(const float4*)(m_state + idx);
    float4 mp4 = ld_bf4(mpb + idx);
    float4 pg4 = ld_bf4(preg + idx);
    float4 pf4 = ld_bf4(pre + idx);
    float4 pi4 = ld_bf4(pre + 4194304 + idx);
    float4 po4 = ld_bf4(pre + 8388608 + idx);
    float4 xf4 = *(const float4*)(proj + 262144 + b * 1024 + col);
    float4 xi4 = *(const float4*)(proj + 524288 + b * 1024 + col);
    float4 xo4 = *(const float4*)(proj + 786432 + b * 1024 + col);
    float4 bg4 = *(const float4*)(b_g + col);
    float4 bf4 = *(const float4*)(b_uf + col);
    float4 bi4 = *(const float4*)(b_ui + col);
    float4 bo4 = *(const float4*)(b_uo + col);

    float4 om, oh;
    {
        float mp2 = pg4.x + bg4.x + mp4.x;
        float fg = sig(pf4.x + bf4.x + xf4.x);
        float ig = sig(pi4.x + bi4.x + xi4.x);
        float og = sig(po4.x + bo4.x + xo4.x);
        om.x = sig(m4.x * fg + 1.0f) + mp2 * sig(ig);
        oh.x = tanhf(m4.x) * sig(og);
    }
    {
        float mp2 = pg4.y + bg4.y + mp4.y;
        float fg = sig(pf4.y + bf4.y + xf4.y);
        float ig = sig(pi4.y + bi4.y + xi4.y);
        float og = sig(po4.y + bo4.y + xo4.y);
        om.y = sig(m4.y * fg + 1.0f) + mp2 * sig(ig);
        oh.y = tanhf(m4.y) * sig(og);
    }
    {
        float mp2 = pg4.z + bg4.z + mp4.z;
        float fg = sig(pf4.z + bf4.z + xf4.z);
        float ig = sig(pi4.z + bi4.z + xi4.z);
        float og = sig(po4.z + bo4.z + xo4.z);
        om.z = sig(m4.z * fg + 1.0f) + mp2 * sig(ig);
        oh.z = tanhf(m4.z) * sig(og);
    }
    {
        float mp2 = pg4.w + bg4.w + mp4.w;
        float fg = sig(pf4.w + bf4.w + xf4.w);
        float ig = sig(pi4.w + bi4.w + xi4.w);
        float og = sig(po4.w + bo4.w + xo4.w);
        om.w = sig(m4.w * fg + 1.0f) + mp2 * sig(ig);
        oh.w = tanhf(m4.w) * sig(og);
    }

    *(float4*)(out_mem + idx) = om;
    *(float4*)(out_hid + idx) = oh;
}

extern "C" void kernel_launch(void* const* d_in, const int* in_sizes, int n_in,
                              void* d_out, int out_size, void* d_ws, size_t ws_size,
                              hipStream_t stream)
{
    const float* inputs  = (const float*)d_in[0];
    const float* h_state = (const float*)d_in[1];
    const float* m_state = (const float*)d_in[2];
    const float* W_emb   = (const float*)d_in[3];
    const float* b_emb   = (const float*)d_in[4];
    const float* W_g     = (const float*)d_in[5];
    const float* b_g     = (const float*)d_in[6];
    const float* W_wf    = (const float*)d_in[7];
    const float* W_wi    = (const float*)d_in[8];
    const float* W_wo    = (const float*)d_in[9];
    const float* W_uf    = (const float*)d_in[10];
    const float* b_uf    = (const float*)d_in[11];
    const float* W_ui    = (const float*)d_in[12];
    const float* b_ui    = (const float*)d_in[13];
    const float* W_uo    = (const float*)d_in[14];
    const float* b_uo    = (const float*)d_in[15];

    char* wsb = (char*)d_ws;
    float* proj = (float*)wsb;                           // 4 MB
    bf16*  hmp  = (bf16*)(wsb + 4u  * 1048576u);         // 8 MB: hbf then mpb
    bf16*  wt   = (bf16*)(wsb + 12u * 1048576u);         // 16 MB (8 x 2MB planes)
    bf16*  xbf  = (bf16*)(wsb + 28u * 1048576u);         // 0.5 MB
    bf16*  pre  = (bf16*)(wsb + 29u * 1048576u);         // 24 MB (3 planes)
    bf16*  preg = (bf16*)(wsb + 20u * 1048576u);         // 8 MB (reuses wt planes 4..7)

    float* out_mem = (float*)d_out;
    float* out_hid = out_mem + (size_t)4096 * 1024;

    // prep: 8192 transpose blocks + 2048 h-cast + 128 x-cast
    k_prep<<<dim3(10368), dim3(256), 0, stream>>>(
        W_g, W_uf, W_ui, W_uo, W_emb, W_wf, W_wi, W_wo,
        h_state, inputs, wt, hmp, xbf);

    // GEMM-1: gate pre-acts + input projections
    k_gemm1<<<dim3(832), dim3(256), 0, stream>>>(
        hmp, xbf, wt, b_emb, pre, proj);

    // attention -> mpb (overwrites hbf slot)
    k_attn<<<dim3(256 * 8), dim3(256), 0, stream>>>(m_state, proj, hmp);

    // GEMM-2: mp@W_g -> preg (wt planes 4..7 are dead now)
    k_gemm2<<<dim3(512), dim3(256), 0, stream>>>(hmp, wt, preg);

    // epilogue -> outputs
    k_epi<<<dim3(4096), dim3(256), 0, stream>>>(
        m_state, hmp, preg, pre, proj,
        b_g, b_uf, b_ui, b_uo, out_mem, out_hid);
}